// Round 3
// baseline (870.527 us; speedup 1.0000x reference)
//
#include <hip/hip_runtime.h>
#include <hip/hip_bf16.h>

#define NN 4096

typedef unsigned short u16;
using bf16x8 = __attribute__((ext_vector_type(8))) short;
using f32x4  = __attribute__((ext_vector_type(4))) float;
using u32x4  = __attribute__((ext_vector_type(4))) unsigned int;

// round-to-nearest-even f32 -> bf16 bits
__device__ inline u16 f2bf(float f) {
    union { float f; unsigned u; } c; c.f = f;
    unsigned r = (c.u + 0x7fffu + ((c.u >> 16) & 1u)) >> 16;
    return (u16)r;
}

__device__ inline void gld16(const void* g, void* l) {
    __builtin_amdgcn_global_load_lds(
        (const __attribute__((address_space(1))) void*)g,
        (__attribute__((address_space(3))) void*)l, 16, 0, 0);
}

__device__ inline bf16x8 negbf(bf16x8 v) {
    u32x4 u; __builtin_memcpy(&u, &v, 16);
    u ^= 0x80008000u;
    bf16x8 r; __builtin_memcpy(&r, &u, 16);
    return r;
}

// ---------------- f32 -> bf16 convert (8 elems/thread) ----------------
__global__ __launch_bounds__(256) void cvt_bf16(const float* __restrict__ s,
                                                u16* __restrict__ d) {
    size_t i = ((size_t)blockIdx.x * 256 + threadIdx.x) * 8;
    float4 v0 = *(const float4*)(s + i);
    float4 v1 = *(const float4*)(s + i + 4);
    bf16x8 o;
    o[0] = (short)f2bf(v0.x); o[1] = (short)f2bf(v0.y);
    o[2] = (short)f2bf(v0.z); o[3] = (short)f2bf(v0.w);
    o[4] = (short)f2bf(v1.x); o[5] = (short)f2bf(v1.y);
    o[6] = (short)f2bf(v1.z); o[7] = (short)f2bf(v1.w);
    *(bf16x8*)(d + i) = o;
}

// ---------------- transpose + convert: d[m][k] = bf16(s[k][m]) ----------------
__global__ __launch_bounds__(256) void tr_cvt(const float* __restrict__ s,
                                              u16* __restrict__ d) {
    __shared__ float t[32][33];
    int x  = blockIdx.x * 32 + threadIdx.x;
    int y0 = blockIdx.y * 32;
#pragma unroll
    for (int j = 0; j < 32; j += 8)
        t[threadIdx.y + j][threadIdx.x] = s[(size_t)(y0 + threadIdx.y + j) * NN + x];
    __syncthreads();
    int x2 = blockIdx.y * 32 + threadIdx.x;
    int y2 = blockIdx.x * 32;
#pragma unroll
    for (int j = 0; j < 32; j += 8)
        d[(size_t)(y2 + threadIdx.y + j) * NN + x2] = f2bf(t[threadIdx.x][threadIdx.y + j]);
}

// Swizzle: physical 16B-block p at LDS row r holds logical block p ^ ((r>>1)&3).
// Staged via inverse-permuted GLOBAL source (gld_lds dest linear, rule #21);
// read with the same XOR. Makes each 16-lane ds_read_b128 phase cover all 8
// four-bank clusters exactly twice -> conflict-free.

// ---------------- pass 1: Rt = NT(W, x), dbuf + swizzle ----------------
__global__ __launch_bounds__(256) void gemm_nt_dual(
    const u16* __restrict__ A0, const u16* __restrict__ A1,
    const u16* __restrict__ B,
    u16* __restrict__ C0, u16* __restrict__ C1) {
    __shared__ u16 sm[2][2][4096];   // [buf][A,B][128*32]
    const u16* A = blockIdx.z ? A1 : A0;
    u16*       C = blockIdx.z ? C1 : C0;

    const int tid  = threadIdx.x;
    const int lane = tid & 63;
    const int wid  = tid >> 6;
    const int wm   = (wid >> 1) * 64;
    const int wn   = (wid & 1) * 64;
    const int brow = blockIdx.y * 128;
    const int bcol = blockIdx.x * 128;

    f32x4 acc[4][4] = {};

    const int r0 = tid >> 2;
    const int lb = (tid & 3) ^ ((r0 >> 1) & 3);     // logical block to fetch
    const size_t aoff0 = (size_t)(brow + r0) * NN + lb * 8;
    const size_t aoff1 = aoff0 + (size_t)64 * NN;
    const size_t boff0 = (size_t)(bcol + r0) * NN + lb * 8;
    const size_t boff1 = boff0 + (size_t)64 * NN;
    const int rl = lane & 15;
    const int kg = (((lane >> 4) ^ ((rl >> 1) & 3))) * 8;  // swizzled read offset

#define STAGE1(buf, kk) do { \
    gld16(A + aoff0 + (kk), &sm[buf][0][tid * 8]); \
    gld16(A + aoff1 + (kk), &sm[buf][0][2048 + tid * 8]); \
    gld16(B + boff0 + (kk), &sm[buf][1][tid * 8]); \
    gld16(B + boff1 + (kk), &sm[buf][1][2048 + tid * 8]); \
} while (0)

    auto compute = [&](int buf) {
        bf16x8 a[4], b[4];
#pragma unroll
        for (int i = 0; i < 4; i++)
            a[i] = *(const bf16x8*)&sm[buf][0][(wm + i * 16 + rl) * 32 + kg];
#pragma unroll
        for (int j = 0; j < 4; j++)
            b[j] = *(const bf16x8*)&sm[buf][1][(wn + j * 16 + rl) * 32 + kg];
#pragma unroll
        for (int i = 0; i < 4; i++)
#pragma unroll
            for (int j = 0; j < 4; j++)
                acc[i][j] = __builtin_amdgcn_mfma_f32_16x16x32_bf16(a[i], b[j], acc[i][j], 0, 0, 0);
    };

    STAGE1(0, 0);
    __syncthreads();
    int cur = 0;
    for (int t = 0; t < NN / 32 - 1; t++) {
        STAGE1(cur ^ 1, (t + 1) * 32);
        compute(cur);
        __syncthreads();
        cur ^= 1;
    }
    compute(cur);

    const int rg = (lane >> 4) * 4;
#pragma unroll
    for (int i = 0; i < 4; i++)
#pragma unroll
        for (int j = 0; j < 4; j++) {
            int col = bcol + wn + j * 16 + (lane & 15);
#pragma unroll
            for (int r = 0; r < 4; r++) {
                int row = brow + wm + i * 16 + rg + r;
                C[(size_t)row * NN + col] = f2bf(acc[i][j][r]);
            }
        }
#undef STAGE1
}

// ---------------- pass 2: fused dual complex GEMM, dbuf + swizzle ----------------
// C_r[m,n] = sum_k Ar[m,k]Br[n,k] - Ai[m,k]Bi[n,k]
// C_i[m,n] = sum_k Ar[m,k]Bi[n,k] + Ai[m,k]Br[n,k]
__global__ __launch_bounds__(256, 2) void gemm_pass2(
    const u16* __restrict__ Ar, const u16* __restrict__ Ai,
    const u16* __restrict__ Br, const u16* __restrict__ Bi,
    float* __restrict__ Out) {
    __shared__ u16 sm[2][4][4096];   // [buf][Ar,Ai,Br,Bi][128*32] = 64 KB

    const int tid  = threadIdx.x;
    const int lane = tid & 63;
    const int wid  = tid >> 6;
    const int wm   = (wid >> 1) * 64;
    const int wn   = (wid & 1) * 64;
    const int brow = blockIdx.y * 128;
    const int bcol = blockIdx.x * 128;

    f32x4 accr[4][4] = {};
    f32x4 acci[4][4] = {};

    const int r0 = tid >> 2;
    const int lb = (tid & 3) ^ ((r0 >> 1) & 3);
    const size_t moff0 = (size_t)(brow + r0) * NN + lb * 8;
    const size_t moff1 = moff0 + (size_t)64 * NN;
    const size_t noff0 = (size_t)(bcol + r0) * NN + lb * 8;
    const size_t noff1 = noff0 + (size_t)64 * NN;
    const int rl = lane & 15;
    const int kg = (((lane >> 4) ^ ((rl >> 1) & 3))) * 8;

#define STAGE2(buf, kk) do { \
    gld16(Ar + moff0 + (kk), &sm[buf][0][tid * 8]); \
    gld16(Ar + moff1 + (kk), &sm[buf][0][2048 + tid * 8]); \
    gld16(Ai + moff0 + (kk), &sm[buf][1][tid * 8]); \
    gld16(Ai + moff1 + (kk), &sm[buf][1][2048 + tid * 8]); \
    gld16(Br + noff0 + (kk), &sm[buf][2][tid * 8]); \
    gld16(Br + noff1 + (kk), &sm[buf][2][2048 + tid * 8]); \
    gld16(Bi + noff0 + (kk), &sm[buf][3][tid * 8]); \
    gld16(Bi + noff1 + (kk), &sm[buf][3][2048 + tid * 8]); \
} while (0)

    auto compute = [&](int buf) {
        bf16x8 ar[4], ai[4], br[4], bi[4];
#pragma unroll
        for (int i = 0; i < 4; i++) {
            ar[i] = *(const bf16x8*)&sm[buf][0][(wm + i * 16 + rl) * 32 + kg];
            ai[i] = *(const bf16x8*)&sm[buf][1][(wm + i * 16 + rl) * 32 + kg];
        }
#pragma unroll
        for (int j = 0; j < 4; j++) {
            br[j] = *(const bf16x8*)&sm[buf][2][(wn + j * 16 + rl) * 32 + kg];
            bi[j] = *(const bf16x8*)&sm[buf][3][(wn + j * 16 + rl) * 32 + kg];
        }
        // acci chain first (uses ai positive)
#pragma unroll
        for (int i = 0; i < 4; i++)
#pragma unroll
            for (int j = 0; j < 4; j++) {
                acci[i][j] = __builtin_amdgcn_mfma_f32_16x16x32_bf16(ar[i], bi[j], acci[i][j], 0, 0, 0);
                acci[i][j] = __builtin_amdgcn_mfma_f32_16x16x32_bf16(ai[i], br[j], acci[i][j], 0, 0, 0);
            }
#pragma unroll
        for (int i = 0; i < 4; i++) ai[i] = negbf(ai[i]);
#pragma unroll
        for (int i = 0; i < 4; i++)
#pragma unroll
            for (int j = 0; j < 4; j++) {
                accr[i][j] = __builtin_amdgcn_mfma_f32_16x16x32_bf16(ar[i], br[j], accr[i][j], 0, 0, 0);
                accr[i][j] = __builtin_amdgcn_mfma_f32_16x16x32_bf16(ai[i], bi[j], accr[i][j], 0, 0, 0);
            }
    };

    STAGE2(0, 0);
    __syncthreads();
    int cur = 0;
    for (int t = 0; t < NN / 32 - 1; t++) {
        STAGE2(cur ^ 1, (t + 1) * 32);
        compute(cur);
        __syncthreads();
        cur ^= 1;
    }
    compute(cur);

    const int rg = (lane >> 4) * 4;
#pragma unroll
    for (int i = 0; i < 4; i++)
#pragma unroll
        for (int j = 0; j < 4; j++) {
            int col = bcol + wn + j * 16 + (lane & 15);
#pragma unroll
            for (int r = 0; r < 4; r++) {
                int row = brow + wm + i * 16 + rg + r;
                Out[(size_t)row * (2 * NN) + col]      = accr[i][j][r];
                Out[(size_t)row * (2 * NN) + NN + col] = acci[i][j][r];
            }
        }
#undef STAGE2
}

extern "C" void kernel_launch(void* const* d_in, const int* in_sizes, int n_in,
                              void* d_out, int out_size, void* d_ws, size_t ws_size,
                              hipStream_t stream) {
    const float* x  = (const float*)d_in[0];
    const float* Wr = (const float*)d_in[1];
    const float* Wi = (const float*)d_in[2];
    float* out = (float*)d_out;

    const size_t SZ = (size_t)NN * NN;
    u16* ws  = (u16*)d_ws;
    u16* xb  = ws;            // slot 0: bf16 x        (later reused: WrT)
    u16* Wrb = ws + SZ;       // slot 1: bf16 W_r      (later reused: WiT)
    u16* Wib = ws + 2 * SZ;   // slot 2: bf16 W_i
    u16* Rtr = ws + 3 * SZ;   // slot 3: R_r^T bf16
    u16* Rti = ws + 4 * SZ;   // slot 4: R_i^T bf16

    // 1) convert inputs to bf16
    cvt_bf16<<<8192, 256, 0, stream>>>(x,  xb);
    cvt_bf16<<<8192, 256, 0, stream>>>(Wr, Wrb);
    cvt_bf16<<<8192, 256, 0, stream>>>(Wi, Wib);

    // 2) pass 1: Rt_r = NT(W_r, x), Rt_i = NT(W_i, x)
    gemm_nt_dual<<<dim3(32, 32, 2), 256, 0, stream>>>(Wrb, Wib, xb, Rtr, Rti);

    // 3) transposed bf16 weights (reuse slots 0,1 — xb/Wrb dead after pass 1)
    u16* WrT = xb;
    u16* WiT = Wrb;
    tr_cvt<<<dim3(128, 128), dim3(32, 8), 0, stream>>>(Wr, WrT);
    tr_cvt<<<dim3(128, 128), dim3(32, 8), 0, stream>>>(Wi, WiT);

    // 4) pass 2: fused dual complex GEMM -> d_out [NN][2*NN]
    gemm_pass2<<<dim3(32, 32), 256, 0, stream>>>(WrT, WiT, Rtr, Rti, out);
}

// Round 4
// 786.487 us; speedup vs baseline: 1.1069x; 1.1069x over previous
//
#include <hip/hip_runtime.h>
#include <hip/hip_bf16.h>

#define NN 4096

typedef unsigned short u16;
using bf16x8 = __attribute__((ext_vector_type(8))) short;
using f32x4  = __attribute__((ext_vector_type(4))) float;
using u32x4  = __attribute__((ext_vector_type(4))) unsigned int;

// round-to-nearest-even f32 -> bf16 bits
__device__ inline u16 f2bf(float f) {
    union { float f; unsigned u; } c; c.f = f;
    unsigned r = (c.u + 0x7fffu + ((c.u >> 16) & 1u)) >> 16;
    return (u16)r;
}

__device__ inline void gld16(const void* g, void* l) {
    __builtin_amdgcn_global_load_lds(
        (const __attribute__((address_space(1))) void*)g,
        (__attribute__((address_space(3))) void*)l, 16, 0, 0);
}

__device__ inline bf16x8 negbf(bf16x8 v) {
    u32x4 u; __builtin_memcpy(&u, &v, 16);
    u ^= 0x80008000u;
    bf16x8 r; __builtin_memcpy(&r, &u, 16);
    return r;
}

// Bijective XCD-region block swizzle: 1024 blocks -> 32x32 tile grid.
// xcd = bid&7 owns an 8x16-tile region (all 8 regions tile the grid);
// blocks sharing A/B panels co-reside on one XCD's L2.
__device__ inline void swz_tile(int bid, int& brow, int& bcol) {
    const int xcd   = bid & 7;
    const int local = bid >> 3;          // 0..127
    const int rr    = xcd >> 1;          // 0..3  (region row)
    const int rc    = xcd & 1;           // 0..1  (region col)
    brow = (rr * 8  + (local >> 4)) * 128;
    bcol = (rc * 16 + (local & 15)) * 128;
}

// ---------------- f32 -> bf16 convert (8 elems/thread) ----------------
__global__ __launch_bounds__(256) void cvt_bf16(const float* __restrict__ s,
                                                u16* __restrict__ d) {
    size_t i = ((size_t)blockIdx.x * 256 + threadIdx.x) * 8;
    float4 v0 = *(const float4*)(s + i);
    float4 v1 = *(const float4*)(s + i + 4);
    bf16x8 o;
    o[0] = (short)f2bf(v0.x); o[1] = (short)f2bf(v0.y);
    o[2] = (short)f2bf(v0.z); o[3] = (short)f2bf(v0.w);
    o[4] = (short)f2bf(v1.x); o[5] = (short)f2bf(v1.y);
    o[6] = (short)f2bf(v1.z); o[7] = (short)f2bf(v1.w);
    *(bf16x8*)(d + i) = o;
}

// ---------------- transpose + convert: d[m][k] = bf16(s[k][m]) ----------------
__global__ __launch_bounds__(256) void tr_cvt(const float* __restrict__ s,
                                              u16* __restrict__ d) {
    __shared__ float t[32][33];
    int x  = blockIdx.x * 32 + threadIdx.x;
    int y0 = blockIdx.y * 32;
#pragma unroll
    for (int j = 0; j < 32; j += 8)
        t[threadIdx.y + j][threadIdx.x] = s[(size_t)(y0 + threadIdx.y + j) * NN + x];
    __syncthreads();
    int x2 = blockIdx.y * 32 + threadIdx.x;
    int y2 = blockIdx.x * 32;
#pragma unroll
    for (int j = 0; j < 32; j += 8)
        d[(size_t)(y2 + threadIdx.y + j) * NN + x2] = f2bf(t[threadIdx.x][threadIdx.y + j]);
}

// LDS swizzle (both GEMMs): physical 16B-block p at row r holds logical block
// p ^ ((r>>1)&3). Staged via inverse-permuted GLOBAL source (gld_lds dest
// linear, rule #21); read back with the same XOR. Conflict-free (R3: 3.35e7->0).

// ---------------- pass 1 (FUSED): Rtr = NT(Wr,x), Rti = NT(Wi,x) ----------------
// Stages Wr-, Wi-, x-tiles once; x fragments feed both accumulator chains.
__global__ __launch_bounds__(256, 2) void gemm_pass1(
    const u16* __restrict__ Ar, const u16* __restrict__ Ai,
    const u16* __restrict__ B,
    u16* __restrict__ Cr, u16* __restrict__ Ci) {
    __shared__ u16 sm[2][3][4096];   // [buf][Wr,Wi,x][128*32] = 48 KB

    int brow, bcol;
    swz_tile(blockIdx.x, brow, bcol);

    const int tid  = threadIdx.x;
    const int lane = tid & 63;
    const int wid  = tid >> 6;
    const int wm   = (wid >> 1) * 64;
    const int wn   = (wid & 1) * 64;

    f32x4 accr[4][4] = {};
    f32x4 acci[4][4] = {};

    const int r0 = tid >> 2;
    const int lb = (tid & 3) ^ ((r0 >> 1) & 3);
    const size_t aoff0 = (size_t)(brow + r0) * NN + lb * 8;
    const size_t aoff1 = aoff0 + (size_t)64 * NN;
    const size_t boff0 = (size_t)(bcol + r0) * NN + lb * 8;
    const size_t boff1 = boff0 + (size_t)64 * NN;
    const int rl = lane & 15;
    const int kg = ((lane >> 4) ^ ((rl >> 1) & 3)) * 8;

#define STG1(buf, kk) do { \
    gld16(Ar + aoff0 + (kk), &sm[buf][0][tid * 8]); \
    gld16(Ar + aoff1 + (kk), &sm[buf][0][2048 + tid * 8]); \
    gld16(Ai + aoff0 + (kk), &sm[buf][1][tid * 8]); \
    gld16(Ai + aoff1 + (kk), &sm[buf][1][2048 + tid * 8]); \
    gld16(B  + boff0 + (kk), &sm[buf][2][tid * 8]); \
    gld16(B  + boff1 + (kk), &sm[buf][2][2048 + tid * 8]); \
} while (0)

    auto compute = [&](int buf) {
        bf16x8 ar[4], ai[4], b[4];
#pragma unroll
        for (int i = 0; i < 4; i++) {
            ar[i] = *(const bf16x8*)&sm[buf][0][(wm + i * 16 + rl) * 32 + kg];
            ai[i] = *(const bf16x8*)&sm[buf][1][(wm + i * 16 + rl) * 32 + kg];
        }
#pragma unroll
        for (int j = 0; j < 4; j++)
            b[j] = *(const bf16x8*)&sm[buf][2][(wn + j * 16 + rl) * 32 + kg];
#pragma unroll
        for (int i = 0; i < 4; i++)
#pragma unroll
            for (int j = 0; j < 4; j++) {
                accr[i][j] = __builtin_amdgcn_mfma_f32_16x16x32_bf16(ar[i], b[j], accr[i][j], 0, 0, 0);
                acci[i][j] = __builtin_amdgcn_mfma_f32_16x16x32_bf16(ai[i], b[j], acci[i][j], 0, 0, 0);
            }
    };

    STG1(0, 0);
    __syncthreads();
    int cur = 0;
    for (int t = 0; t < NN / 32 - 1; t++) {
        STG1(cur ^ 1, (t + 1) * 32);
        compute(cur);
        __syncthreads();
        cur ^= 1;
    }
    compute(cur);

    const int rg = (lane >> 4) * 4;
#pragma unroll
    for (int i = 0; i < 4; i++)
#pragma unroll
        for (int j = 0; j < 4; j++) {
            int col = bcol + wn + j * 16 + rl;
#pragma unroll
            for (int r = 0; r < 4; r++) {
                int row = brow + wm + i * 16 + rg + r;
                Cr[(size_t)row * NN + col] = f2bf(accr[i][j][r]);
                Ci[(size_t)row * NN + col] = f2bf(acci[i][j][r]);
            }
        }
#undef STG1
}

// ---------------- pass 2: fused dual complex GEMM, dbuf + swizzle ----------------
// C_r[m,n] = sum_k Ar[m,k]Br[n,k] - Ai[m,k]Bi[n,k]
// C_i[m,n] = sum_k Ar[m,k]Bi[n,k] + Ai[m,k]Br[n,k]
__global__ __launch_bounds__(256, 2) void gemm_pass2(
    const u16* __restrict__ Ar, const u16* __restrict__ Ai,
    const u16* __restrict__ Br, const u16* __restrict__ Bi,
    float* __restrict__ Out) {
    __shared__ u16 sm[2][4][4096];   // [buf][Ar,Ai,Br,Bi][128*32] = 64 KB

    int brow, bcol;
    swz_tile(blockIdx.x, brow, bcol);

    const int tid  = threadIdx.x;
    const int lane = tid & 63;
    const int wid  = tid >> 6;
    const int wm   = (wid >> 1) * 64;
    const int wn   = (wid & 1) * 64;

    f32x4 accr[4][4] = {};
    f32x4 acci[4][4] = {};

    const int r0 = tid >> 2;
    const int lb = (tid & 3) ^ ((r0 >> 1) & 3);
    const size_t moff0 = (size_t)(brow + r0) * NN + lb * 8;
    const size_t moff1 = moff0 + (size_t)64 * NN;
    const size_t noff0 = (size_t)(bcol + r0) * NN + lb * 8;
    const size_t noff1 = noff0 + (size_t)64 * NN;
    const int rl = lane & 15;
    const int kg = ((lane >> 4) ^ ((rl >> 1) & 3)) * 8;

#define STAGE2(buf, kk) do { \
    gld16(Ar + moff0 + (kk), &sm[buf][0][tid * 8]); \
    gld16(Ar + moff1 + (kk), &sm[buf][0][2048 + tid * 8]); \
    gld16(Ai + moff0 + (kk), &sm[buf][1][tid * 8]); \
    gld16(Ai + moff1 + (kk), &sm[buf][1][2048 + tid * 8]); \
    gld16(Br + noff0 + (kk), &sm[buf][2][tid * 8]); \
    gld16(Br + noff1 + (kk), &sm[buf][2][2048 + tid * 8]); \
    gld16(Bi + noff0 + (kk), &sm[buf][3][tid * 8]); \
    gld16(Bi + noff1 + (kk), &sm[buf][3][2048 + tid * 8]); \
} while (0)

    auto compute = [&](int buf) {
        bf16x8 ar[4], ai[4], br[4], bi[4];
#pragma unroll
        for (int i = 0; i < 4; i++) {
            ar[i] = *(const bf16x8*)&sm[buf][0][(wm + i * 16 + rl) * 32 + kg];
            ai[i] = *(const bf16x8*)&sm[buf][1][(wm + i * 16 + rl) * 32 + kg];
        }
#pragma unroll
        for (int j = 0; j < 4; j++) {
            br[j] = *(const bf16x8*)&sm[buf][2][(wn + j * 16 + rl) * 32 + kg];
            bi[j] = *(const bf16x8*)&sm[buf][3][(wn + j * 16 + rl) * 32 + kg];
        }
        // acci chain first (uses ai positive)
#pragma unroll
        for (int i = 0; i < 4; i++)
#pragma unroll
            for (int j = 0; j < 4; j++) {
                acci[i][j] = __builtin_amdgcn_mfma_f32_16x16x32_bf16(ar[i], bi[j], acci[i][j], 0, 0, 0);
                acci[i][j] = __builtin_amdgcn_mfma_f32_16x16x32_bf16(ai[i], br[j], acci[i][j], 0, 0, 0);
            }
#pragma unroll
        for (int i = 0; i < 4; i++) ai[i] = negbf(ai[i]);
#pragma unroll
        for (int i = 0; i < 4; i++)
#pragma unroll
            for (int j = 0; j < 4; j++) {
                accr[i][j] = __builtin_amdgcn_mfma_f32_16x16x32_bf16(ar[i], br[j], accr[i][j], 0, 0, 0);
                accr[i][j] = __builtin_amdgcn_mfma_f32_16x16x32_bf16(ai[i], bi[j], accr[i][j], 0, 0, 0);
            }
    };

    STAGE2(0, 0);
    __syncthreads();
    int cur = 0;
    for (int t = 0; t < NN / 32 - 1; t++) {
        STAGE2(cur ^ 1, (t + 1) * 32);
        compute(cur);
        __syncthreads();
        cur ^= 1;
    }
    compute(cur);

    const int rg = (lane >> 4) * 4;
#pragma unroll
    for (int i = 0; i < 4; i++)
#pragma unroll
        for (int j = 0; j < 4; j++) {
            int col = bcol + wn + j * 16 + rl;
#pragma unroll
            for (int r = 0; r < 4; r++) {
                int row = brow + wm + i * 16 + rg + r;
                Out[(size_t)row * (2 * NN) + col]      = accr[i][j][r];
                Out[(size_t)row * (2 * NN) + NN + col] = acci[i][j][r];
            }
        }
#undef STAGE2
}

extern "C" void kernel_launch(void* const* d_in, const int* in_sizes, int n_in,
                              void* d_out, int out_size, void* d_ws, size_t ws_size,
                              hipStream_t stream) {
    const float* x  = (const float*)d_in[0];
    const float* Wr = (const float*)d_in[1];
    const float* Wi = (const float*)d_in[2];
    float* out = (float*)d_out;

    const size_t SZ = (size_t)NN * NN;
    u16* ws  = (u16*)d_ws;
    u16* xb  = ws;            // slot 0: bf16 x        (later reused: WrT)
    u16* Wrb = ws + SZ;       // slot 1: bf16 W_r      (later reused: WiT)
    u16* Wib = ws + 2 * SZ;   // slot 2: bf16 W_i
    u16* Rtr = ws + 3 * SZ;   // slot 3: R_r^T bf16
    u16* Rti = ws + 4 * SZ;   // slot 4: R_i^T bf16

    // 1) convert inputs to bf16
    cvt_bf16<<<8192, 256, 0, stream>>>(x,  xb);
    cvt_bf16<<<8192, 256, 0, stream>>>(Wr, Wrb);
    cvt_bf16<<<8192, 256, 0, stream>>>(Wi, Wib);

    // 2) fused pass 1: Rt_r = NT(W_r, x), Rt_i = NT(W_i, x) in one kernel
    gemm_pass1<<<1024, 256, 0, stream>>>(Wrb, Wib, xb, Rtr, Rti);

    // 3) transposed bf16 weights (reuse slots 0,1 — xb/Wrb dead after pass 1)
    u16* WrT = xb;
    u16* WiT = Wrb;
    tr_cvt<<<dim3(128, 128), dim3(32, 8), 0, stream>>>(Wr, WrT);
    tr_cvt<<<dim3(128, 128), dim3(32, 8), 0, stream>>>(Wi, WiT);

    // 4) pass 2: fused dual complex GEMM -> d_out [NN][2*NN]
    gemm_pass2<<<1024, 256, 0, stream>>>(WrT, WiT, Rtr, Rti, out);
}